// Round 6
// baseline (258.111 us; speedup 1.0000x reference)
//
#include <hip/hip_runtime.h>
#include <math.h>

#define BS 4
#define C 4
#define N 2048
#define D 16
#define KNN 32
#define M 64

// ---------------------------------------------------------------------------
// Kernel 1: exact 32-NN (sorted ascending, ties -> lower index) per (b,c,n).
// One wave per row; 8 rows (same b,c) per 512-thread block.
// Per-lane sorted head-4 of u64 keys. Extraction: single u32 min-reduce on
// dist bits (DPP on even waves / shfl on odd waves -> pipe balancing),
// ballot+readlane winner resolution, exact tie path behind a uniform branch.
// Distance arithmetic replicates numpy f32 semantics bit-exactly:
//   inner = (x*x' + y*y') + z*z'      (sequential, no fma)
//   quad  = (x*x + y*y) + z*z
//   dist  = ((-2*inner) + quad_j) + quad_n
// ---------------------------------------------------------------------------

__device__ __forceinline__ unsigned int umin_u32(unsigned int a, unsigned int b) {
    return a < b ? a : b;
}

// VALU-pipe wave64 min-reduce via DPP; uniform result via readlane(63).
#define DPP_MIN_STAGE(v, ctrl)                                                  \
    v = umin_u32(v, (unsigned int)__builtin_amdgcn_update_dpp(                  \
                        (int)0xFFFFFFFF, (int)(v), (ctrl), 0xF, 0xF, false))

__device__ __forceinline__ unsigned int wave_min_dpp(unsigned int v) {
    DPP_MIN_STAGE(v, 0x111);  // row_shr:1
    DPP_MIN_STAGE(v, 0x112);  // row_shr:2
    DPP_MIN_STAGE(v, 0x114);  // row_shr:4
    DPP_MIN_STAGE(v, 0x118);  // row_shr:8
    DPP_MIN_STAGE(v, 0x142);  // row_bcast:15
    DPP_MIN_STAGE(v, 0x143);  // row_bcast:31 -> lane63 = wave min
    return (unsigned int)__builtin_amdgcn_readlane((int)v, 63);
}

// LDS-pipe wave64 min-reduce (ds_swizzle/permute); all lanes hold result.
__device__ __forceinline__ unsigned int wave_min_lds(unsigned int v) {
#pragma unroll
    for (int off = 1; off < 64; off <<= 1)
        v = umin_u32(v, (unsigned int)__shfl_xor((int)v, off));
    return v;
}

__device__ __forceinline__ float np_quad(float x, float y, float z) {
#pragma clang fp contract(off)
    float q = (x * x + y * y) + z * z;
    return q;
}

__device__ __forceinline__ float np_dist(const float4& me, const float4& p) {
#pragma clang fp contract(off)
    float inner = (me.x * p.x + me.y * p.y) + me.z * p.z;
    float dist  = ((-2.0f * inner) + p.w) + me.w;
    return dist;
}

__device__ __forceinline__ unsigned long long dist_key(float dist, int j) {
    unsigned int b = __float_as_uint(dist);
    unsigned int f = b ^ (0x80000000u | (unsigned int)((int)b >> 31));
    return ((unsigned long long)f << 32) | (unsigned int)j;
}

__global__ __launch_bounds__(512) void knn_kernel(const float* __restrict__ pos,
                                                  int* __restrict__ edge_ws,
                                                  float* __restrict__ dist_ws) {
    __shared__ float4 sp[N];                       // {x,y,z,quad} -> 32 KB
    __shared__ unsigned long long res_lds[8][32];  // per-wave sorted results, 2 KB
    const int tid  = threadIdx.x;
    const int lane = tid & 63;
    const int wave = tid >> 6;         // 0..7
    const int row0 = blockIdx.x * 8;   // 8 consecutive rows, same (b,c)
    const int bc   = row0 >> 11;

    const float* posr = pos + (size_t)bc * (N * 3);
    for (int j = tid; j < N; j += 512) {
        float x = posr[3 * j], y = posr[3 * j + 1], z = posr[3 * j + 2];
        sp[j] = make_float4(x, y, z, np_quad(x, y, z));
    }
    __syncthreads();

    const int row = row0 + wave;
    const int n   = row & (N - 1);
    const float4 me = sp[n];   // me.w = quad_n

    const unsigned long long SENT = ~0ull;
    unsigned long long k0 = SENT, k1 = SENT, k2 = SENT, k3 = SENT;

    // ---- build: stream candidates, insert into sorted head-4 ----
#pragma unroll
    for (int jj = 0; jj < 32; ++jj) {
        int j = jj * 64 + lane;
        float4 p = sp[j];
        unsigned long long x = dist_key(np_dist(me, p), j);
        if (j == n) x = SENT;
        { bool c = x < k0; unsigned long long mn = c ? x : k0, mx = c ? k0 : x; k0 = mn; x = mx; }
        { bool c = x < k1; unsigned long long mn = c ? x : k1, mx = c ? k1 : x; k1 = mn; x = mx; }
        { bool c = x < k2; unsigned long long mn = c ? x : k2, mx = c ? k2 : x; k2 = mn; x = mx; }
        k3 = (x < k3) ? x : k3;
    }

    // ---- 32 extraction rounds ----
    const bool use_lds_reduce = (wave & 1);
    int popc = 0;
    unsigned long long thr = 0ull;
    for (int s = 0; s < 32; ++s) {
        unsigned int hd = (unsigned int)(k0 >> 32);
        unsigned int rd = use_lds_reduce ? wave_min_lds(hd) : wave_min_dpp(hd);
        unsigned long long tb = __ballot(hd == rd);
        unsigned int rl;
        if (__popcll(tb) == 1) {
            // common case: unique dist-bit winner; grab its index directly
            int w = (int)(__ffsll((long long)tb) - 1);
            rl = (unsigned int)__builtin_amdgcn_readlane((int)(unsigned int)k0, w);
        } else {
            // exact tie path: min index among dist-tied lanes
            unsigned int lo = (hd == rd) ? (unsigned int)k0 : 0xFFFFFFFFu;
            rl = wave_min_lds(lo);
        }
        bool mine = (hd == rd) && ((unsigned int)k0 == rl);
        if (mine) {
            res_lds[wave][s] = k0;   // 1-lane ds_write_b64 (LDS pipe)
            thr = k0;
            k0 = k1; k1 = k2; k2 = k3; k3 = SENT;
            ++popc;
        }
        if (popc == 4) {
            // exact refill: 4 smallest candidates with key strictly > thr
            k0 = SENT; k1 = SENT; k2 = SENT; k3 = SENT;
#pragma unroll
            for (int jj = 0; jj < 32; ++jj) {
                int j = jj * 64 + lane;
                float4 p = sp[j];
                unsigned long long x = dist_key(np_dist(me, p), j);
                if (j == n) x = SENT;
                if (x <= thr) x = SENT;
                { bool c = x < k0; unsigned long long mn = c ? x : k0, mx = c ? k0 : x; k0 = mn; x = mx; }
                { bool c = x < k1; unsigned long long mn = c ? x : k1, mx = c ? k1 : x; k1 = mn; x = mx; }
                { bool c = x < k2; unsigned long long mn = c ? x : k2, mx = c ? k2 : x; k2 = mn; x = mx; }
                k3 = (x < k3) ? x : k3;
            }
            popc = 0;
        }
    }

    if (lane < 32) {
        unsigned long long k = res_lds[wave][lane];
        unsigned int f = (unsigned int)(k >> 32);
        unsigned int b = (f & 0x80000000u) ? (f ^ 0x80000000u) : ~f;
        edge_ws[(size_t)row * KNN + lane] = (int)(unsigned int)k;
        dist_ws[(size_t)row * KNN + lane] = __uint_as_float(b);
    }
}

// ---------------------------------------------------------------------------
// Kernel 2: angle features + gate + gated aggregation + two 128->64 matvecs.
// One wave per (b,n); 8 consecutive n (same b) per 512-thread block.
// aw kept in natural [m][f] layout, stride 129 -> conflict-free write & read.
// ---------------------------------------------------------------------------
__global__ __launch_bounds__(512) void conv_kernel(
    const float* __restrict__ pos, const float* __restrict__ node_fea,
    const float* __restrict__ node_mask, const float* __restrict__ aw,
    const float* __restrict__ sw, const float* __restrict__ w1,
    const float* __restrict__ w2, const int* __restrict__ edge_ws,
    const float* __restrict__ dist_ws, float* __restrict__ out) {
    __shared__ float aw_s[64 * 129];       // aw[m][f] padded: ~33 KB
    __shared__ float theta_lds[8][128];    // [wave][kk*4+cc]
    __shared__ float gate_lds[8][128];     // [wave][cc*32+kk]
    __shared__ int   edge_lds[8][128];     // [wave][cc*32+kk]
    __shared__ float h_lds[8][128];        // [wave][cc*32+dd]
    __shared__ float gsum_lds[8][4];       // [wave][cc]
    __shared__ float outv[8][65];          // [n-offset][m], padded

    const int tid  = threadIdx.x;
    const int lane = tid & 63;
    const int wave = tid >> 6;             // 0..7

    // stage angle_weight, natural layout, padded stride
    for (int i = tid; i < 64 * 128; i += 512) {
        int m = i >> 7, f = i & 127;
        aw_s[m * 129 + f] = aw[i];
    }

    const int row0 = blockIdx.x * 8;   // (b,n) row base, same b across block
    const int b    = row0 >> 11;
    const int n0   = row0 & (N - 1);
    const int row  = row0 + wave;
    const int n    = row & (N - 1);
    const float mval = node_mask[b * N + n];

    // gate scalar: S = sum_m relu(w1[m]) * w2[m]  (valid since dist > 0)
    float S = 0.f;
    for (int m = 0; m < 64; ++m) S += fmaxf(w1[m], 0.f) * w2[m];

    __syncthreads();

    // ---- Phase A: per (cc,kk) pair: direction, theta, gate ----
#pragma unroll
    for (int it = 0; it < 2; ++it) {
        int p  = it * 64 + lane;
        int cc = p >> 5, kk = p & 31;
        int rowc = (b * C + cc) * N + n;
        int e      = edge_ws[(size_t)rowc * KNN + kk];
        float dist = dist_ws[(size_t)rowc * KNN + kk];
        const float* pp = pos + (size_t)rowc * 3;
        const float* qp = pos + ((size_t)(b * C + cc) * N + e) * 3;
        float dx = qp[0] - pp[0], dy = qp[1] - pp[1], dz = qp[2] - pp[2];
        float nrm = fmaxf(sqrtf(dx * dx + dy * dy + dz * dz), 1e-12f);
        dx /= nrm; dy /= nrm; dz /= nrm;
        int src = lane & 32;   // lane holding kk==0 for this cc-group
        float n0x = __shfl(dx, src), n0y = __shfl(dy, src), n0z = __shfl(dz, src);
        float cosv = (kk == 0) ? 1.f : (dx * n0x + dy * n0y + dz * n0z);
        theta_lds[wave][kk * 4 + cc] = cosv * mval;

        float g = fmaxf(dist * S, 0.f) * mval;
        float gate = 1.f / (1.f + expf(-g));
        gate_lds[wave][cc * 32 + kk] = gate;
        edge_lds[wave][cc * 32 + kk] = e;
        float gs = gate;
#pragma unroll
        for (int off = 1; off < 32; off <<= 1) gs += __shfl_xor(gs, off);
        if (kk == 0) gsum_lds[wave][cc] = gs;
    }
    __syncthreads();

    // ---- Phase B: h[f] = sum_k gate * fea_cat ----
#pragma unroll
    for (int it = 0; it < 2; ++it) {
        int f  = it * 64 + lane;
        int cc = f >> 5, dd = f & 31;
        float h;
        if (dd < 16) {
            float own = node_fea[((size_t)(b * C + cc) * N + n) * D + dd];
            h = own * mval * gsum_lds[wave][cc];
        } else {
            int dd2 = dd - 16;
            const float* nf = node_fea + (size_t)(b * C + cc) * N * D;
            float acc = 0.f;
#pragma unroll 8
            for (int k = 0; k < 32; ++k) {
                int e = edge_lds[wave][cc * 32 + k];
                acc += gate_lds[wave][cc * 32 + k] * nf[e * D + dd2];
            }
            h = acc * mval;
        }
        h_lds[wave][f] = h;
    }
    __syncthreads();

    // ---- Phase C: m = lane; two 128->64 matvecs + epilogue ----
    float fs = 0.f, fe = 0.f;
#pragma unroll 8
    for (int f = 0; f < 128; ++f) {
        fs += aw_s[lane * 129 + f] * theta_lds[wave][f];
        fe += h_lds[wave][f] * sw[f * 64 + lane];
    }
    float v = fs + fe;
    v = (v > 0.f) ? v : 0.01f * v;
    outv[wave][lane] = v * mval;
    __syncthreads();

    // store: thread t -> m = t>>3, n-offset j = t&7
    {
        int m = tid >> 3, j = tid & 7;
        out[((size_t)(b * 64 + m)) * N + n0 + j] = outv[j][m];
    }
}

// ---------------------------------------------------------------------------
extern "C" void kernel_launch(void* const* d_in, const int* in_sizes, int n_in,
                              void* d_out, int out_size, void* d_ws, size_t ws_size,
                              hipStream_t stream) {
    const float* pos       = (const float*)d_in[0];
    const float* node_fea  = (const float*)d_in[1];
    const float* node_mask = (const float*)d_in[2];
    const float* aw        = (const float*)d_in[3];
    const float* sw        = (const float*)d_in[4];
    const float* w1        = (const float*)d_in[5];
    const float* w2        = (const float*)d_in[6];
    float* out = (float*)d_out;

    int*   edge_ws = (int*)d_ws;
    float* dist_ws = (float*)((char*)d_ws + (size_t)BS * C * N * KNN * sizeof(int));

    knn_kernel<<<BS * C * N / 8, 512, 0, stream>>>(pos, edge_ws, dist_ws);
    conv_kernel<<<BS * N / 8, 512, 0, stream>>>(pos, node_fea, node_mask, aw, sw,
                                                w1, w2, edge_ws, dist_ws, out);
}

// Round 7
// 214.634 us; speedup vs baseline: 1.2026x; 1.2026x over previous
//
#include <hip/hip_runtime.h>
#include <math.h>

#define BS 4
#define C 4
#define N 2048
#define D 16
#define KNN 32
#define M 64

// ---------------------------------------------------------------------------
// Kernel 1: exact 32-NN (sorted ascending, ties -> lower index) per (b,c,n).
// One wave per row; 8 rows (same b,c) per 512-thread block.
// Per-lane sorted head-4 of u64 keys. Extraction: 33 rounds (self included,
// first result dropped -- exactly the reference's top-(k+1) semantics).
// Per round: one u32 DPP min-reduce on dist bits (VALU pipe), ballot +
// s_ff1 + readlane winner resolution; exact tie path behind a wave-uniform
// branch. Results collected via 1-lane ds_write_b64 (LDS pipe is idle).
// Distance arithmetic replicates numpy f32 semantics bit-exactly:
//   inner = (x*x' + y*y') + z*z'      (sequential, no fma)
//   quad  = (x*x + y*y) + z*z
//   dist  = ((-2*inner) + quad_j) + quad_n
// ---------------------------------------------------------------------------

__device__ __forceinline__ unsigned int umin_u32(unsigned int a, unsigned int b) {
    return a < b ? a : b;
}

// VALU-pipe wave64 min-reduce via DPP; uniform result via readlane(63).
#define DPP_MIN_STAGE(v, ctrl)                                                  \
    v = umin_u32(v, (unsigned int)__builtin_amdgcn_update_dpp(                  \
                        (int)0xFFFFFFFF, (int)(v), (ctrl), 0xF, 0xF, false))

__device__ __forceinline__ unsigned int wave_min_dpp(unsigned int v) {
    DPP_MIN_STAGE(v, 0x111);  // row_shr:1
    DPP_MIN_STAGE(v, 0x112);  // row_shr:2
    DPP_MIN_STAGE(v, 0x114);  // row_shr:4
    DPP_MIN_STAGE(v, 0x118);  // row_shr:8
    DPP_MIN_STAGE(v, 0x142);  // row_bcast:15
    DPP_MIN_STAGE(v, 0x143);  // row_bcast:31 -> lane63 = wave min
    return (unsigned int)__builtin_amdgcn_readlane((int)v, 63);
}

__device__ __forceinline__ float np_quad(float x, float y, float z) {
#pragma clang fp contract(off)
    float q = (x * x + y * y) + z * z;
    return q;
}

__device__ __forceinline__ float np_dist(const float4& me, const float4& p) {
#pragma clang fp contract(off)
    float inner = (me.x * p.x + me.y * p.y) + me.z * p.z;
    float dist  = ((-2.0f * inner) + p.w) + me.w;
    return dist;
}

__device__ __forceinline__ unsigned long long dist_key(float dist, int j) {
    unsigned int b = __float_as_uint(dist);
    unsigned int f = b ^ (0x80000000u | (unsigned int)((int)b >> 31));
    return ((unsigned long long)f << 32) | (unsigned int)j;
}

__global__ __launch_bounds__(512) void knn_kernel(const float* __restrict__ pos,
                                                  int* __restrict__ edge_ws,
                                                  float* __restrict__ dist_ws) {
    __shared__ float4 sp[N];                       // {x,y,z,quad} -> 32 KB
    __shared__ unsigned long long res_lds[8][32];  // per-wave sorted results, 2 KB
    const int tid  = threadIdx.x;
    const int lane = tid & 63;
    const int wave = tid >> 6;         // 0..7
    const int row0 = blockIdx.x * 8;   // 8 consecutive rows, same (b,c)
    const int bc   = row0 >> 11;

    const float* posr = pos + (size_t)bc * (N * 3);
    for (int j = tid; j < N; j += 512) {
        float x = posr[3 * j], y = posr[3 * j + 1], z = posr[3 * j + 2];
        sp[j] = make_float4(x, y, z, np_quad(x, y, z));
    }
    __syncthreads();

    const int row = row0 + wave;
    const int n   = row & (N - 1);
    const float4 me = sp[n];   // me.w = quad_n

    const unsigned long long SENT = ~0ull;
    unsigned long long k0 = SENT, k1 = SENT, k2 = SENT, k3 = SENT;

    // ---- build: stream candidates (self INCLUDED; dropped at s=0) ----
#pragma unroll
    for (int jj = 0; jj < 32; ++jj) {
        int j = jj * 64 + lane;
        float4 p = sp[j];
        unsigned long long x = dist_key(np_dist(me, p), j);
        { bool c = x < k0; unsigned long long mn = c ? x : k0, mx = c ? k0 : x; k0 = mn; x = mx; }
        { bool c = x < k1; unsigned long long mn = c ? x : k1, mx = c ? k1 : x; k1 = mn; x = mx; }
        { bool c = x < k2; unsigned long long mn = c ? x : k2, mx = c ? k2 : x; k2 = mn; x = mx; }
        k3 = (x < k3) ? x : k3;
    }

    // ---- 33 extraction rounds (round 0 pops self; results for s>=1) ----
    int popc = 0;
    unsigned long long thr = 0ull;
    for (int s = 0; s < KNN + 1; ++s) {
        unsigned int hd = (unsigned int)(k0 >> 32);
        unsigned int rd = wave_min_dpp(hd);
        unsigned long long tb = __ballot(hd == rd);
        unsigned int rl;
        if (__popcll(tb) == 1) {
            // common case: unique dist-bit winner; grab its index directly
            int w = (int)(__ffsll((long long)tb) - 1);
            rl = (unsigned int)__builtin_amdgcn_readlane((int)(unsigned int)k0, w);
        } else {
            // exact tie path: min index among dist-tied lanes
            unsigned int lo = (hd == rd) ? (unsigned int)k0 : 0xFFFFFFFFu;
            rl = wave_min_dpp(lo);
        }
        bool mine = (hd == rd) && ((unsigned int)k0 == rl);
        if (mine) {
            if (s > 0) res_lds[wave][s - 1] = k0;  // 1-lane ds_write_b64
            thr = k0;
            k0 = k1; k1 = k2; k2 = k3; k3 = SENT;
            ++popc;
        }
        if (popc == 4) {
            // exact refill (per-lane): 4 smallest candidates with key > thr
            k0 = SENT; k1 = SENT; k2 = SENT; k3 = SENT;
#pragma unroll
            for (int jj = 0; jj < 32; ++jj) {
                int j = jj * 64 + lane;
                float4 p = sp[j];
                unsigned long long x = dist_key(np_dist(me, p), j);
                if (x <= thr) x = SENT;
                { bool c = x < k0; unsigned long long mn = c ? x : k0, mx = c ? k0 : x; k0 = mn; x = mx; }
                { bool c = x < k1; unsigned long long mn = c ? x : k1, mx = c ? k1 : x; k1 = mn; x = mx; }
                { bool c = x < k2; unsigned long long mn = c ? x : k2, mx = c ? k2 : x; k2 = mn; x = mx; }
                k3 = (x < k3) ? x : k3;
            }
            popc = 0;
        }
    }

    if (lane < 32) {
        unsigned long long k = res_lds[wave][lane];
        unsigned int f = (unsigned int)(k >> 32);
        unsigned int b = (f & 0x80000000u) ? (f ^ 0x80000000u) : ~f;
        edge_ws[(size_t)row * KNN + lane] = (int)(unsigned int)k;
        dist_ws[(size_t)row * KNN + lane] = __uint_as_float(b);
    }
}

// ---------------------------------------------------------------------------
// Kernel 2: angle features + gate + gated aggregation + two 128->64 matvecs.
// One wave per (b,n); 8 consecutive n (same b) per 512-thread block.
// aw kept in natural [m][f] layout, stride 129 -> conflict-free write & read.
// ---------------------------------------------------------------------------
__global__ __launch_bounds__(512) void conv_kernel(
    const float* __restrict__ pos, const float* __restrict__ node_fea,
    const float* __restrict__ node_mask, const float* __restrict__ aw,
    const float* __restrict__ sw, const float* __restrict__ w1,
    const float* __restrict__ w2, const int* __restrict__ edge_ws,
    const float* __restrict__ dist_ws, float* __restrict__ out) {
    __shared__ float aw_s[64 * 129];       // aw[m][f] padded: ~33 KB
    __shared__ float theta_lds[8][128];    // [wave][kk*4+cc]
    __shared__ float gate_lds[8][128];     // [wave][cc*32+kk]
    __shared__ int   edge_lds[8][128];     // [wave][cc*32+kk]
    __shared__ float h_lds[8][128];        // [wave][cc*32+dd]
    __shared__ float gsum_lds[8][4];       // [wave][cc]
    __shared__ float outv[8][65];          // [n-offset][m], padded

    const int tid  = threadIdx.x;
    const int lane = tid & 63;
    const int wave = tid >> 6;             // 0..7

    // stage angle_weight, natural layout, padded stride
    for (int i = tid; i < 64 * 128; i += 512) {
        int m = i >> 7, f = i & 127;
        aw_s[m * 129 + f] = aw[i];
    }

    const int row0 = blockIdx.x * 8;   // (b,n) row base, same b across block
    const int b    = row0 >> 11;
    const int n0   = row0 & (N - 1);
    const int row  = row0 + wave;
    const int n    = row & (N - 1);
    const float mval = node_mask[b * N + n];

    // gate scalar: S = sum_m relu(w1[m]) * w2[m]  (valid since dist > 0)
    float S = 0.f;
    for (int m = 0; m < 64; ++m) S += fmaxf(w1[m], 0.f) * w2[m];

    __syncthreads();

    // ---- Phase A: per (cc,kk) pair: direction, theta, gate ----
#pragma unroll
    for (int it = 0; it < 2; ++it) {
        int p  = it * 64 + lane;
        int cc = p >> 5, kk = p & 31;
        int rowc = (b * C + cc) * N + n;
        int e      = edge_ws[(size_t)rowc * KNN + kk];
        float dist = dist_ws[(size_t)rowc * KNN + kk];
        const float* pp = pos + (size_t)rowc * 3;
        const float* qp = pos + ((size_t)(b * C + cc) * N + e) * 3;
        float dx = qp[0] - pp[0], dy = qp[1] - pp[1], dz = qp[2] - pp[2];
        float nrm = fmaxf(sqrtf(dx * dx + dy * dy + dz * dz), 1e-12f);
        dx /= nrm; dy /= nrm; dz /= nrm;
        int src = lane & 32;   // lane holding kk==0 for this cc-group
        float n0x = __shfl(dx, src), n0y = __shfl(dy, src), n0z = __shfl(dz, src);
        float cosv = (kk == 0) ? 1.f : (dx * n0x + dy * n0y + dz * n0z);
        theta_lds[wave][kk * 4 + cc] = cosv * mval;

        float g = fmaxf(dist * S, 0.f) * mval;
        float gate = 1.f / (1.f + expf(-g));
        gate_lds[wave][cc * 32 + kk] = gate;
        edge_lds[wave][cc * 32 + kk] = e;
        float gs = gate;
#pragma unroll
        for (int off = 1; off < 32; off <<= 1) gs += __shfl_xor(gs, off);
        if (kk == 0) gsum_lds[wave][cc] = gs;
    }
    __syncthreads();

    // ---- Phase B: h[f] = sum_k gate * fea_cat ----
#pragma unroll
    for (int it = 0; it < 2; ++it) {
        int f  = it * 64 + lane;
        int cc = f >> 5, dd = f & 31;
        float h;
        if (dd < 16) {
            float own = node_fea[((size_t)(b * C + cc) * N + n) * D + dd];
            h = own * mval * gsum_lds[wave][cc];
        } else {
            int dd2 = dd - 16;
            const float* nf = node_fea + (size_t)(b * C + cc) * N * D;
            float acc = 0.f;
#pragma unroll 8
            for (int k = 0; k < 32; ++k) {
                int e = edge_lds[wave][cc * 32 + k];
                acc += gate_lds[wave][cc * 32 + k] * nf[e * D + dd2];
            }
            h = acc * mval;
        }
        h_lds[wave][f] = h;
    }
    __syncthreads();

    // ---- Phase C: m = lane; two 128->64 matvecs + epilogue ----
    float fs = 0.f, fe = 0.f;
#pragma unroll 8
    for (int f = 0; f < 128; ++f) {
        fs += aw_s[lane * 129 + f] * theta_lds[wave][f];
        fe += h_lds[wave][f] * sw[f * 64 + lane];
    }
    float v = fs + fe;
    v = (v > 0.f) ? v : 0.01f * v;
    outv[wave][lane] = v * mval;
    __syncthreads();

    // store: thread t -> m = t>>3, n-offset j = t&7
    {
        int m = tid >> 3, j = tid & 7;
        out[((size_t)(b * 64 + m)) * N + n0 + j] = outv[j][m];
    }
}

// ---------------------------------------------------------------------------
extern "C" void kernel_launch(void* const* d_in, const int* in_sizes, int n_in,
                              void* d_out, int out_size, void* d_ws, size_t ws_size,
                              hipStream_t stream) {
    const float* pos       = (const float*)d_in[0];
    const float* node_fea  = (const float*)d_in[1];
    const float* node_mask = (const float*)d_in[2];
    const float* aw        = (const float*)d_in[3];
    const float* sw        = (const float*)d_in[4];
    const float* w1        = (const float*)d_in[5];
    const float* w2        = (const float*)d_in[6];
    float* out = (float*)d_out;

    int*   edge_ws = (int*)d_ws;
    float* dist_ws = (float*)((char*)d_ws + (size_t)BS * C * N * KNN * sizeof(int));

    knn_kernel<<<BS * C * N / 8, 512, 0, stream>>>(pos, edge_ws, dist_ws);
    conv_kernel<<<BS * N / 8, 512, 0, stream>>>(pos, node_fea, node_mask, aw, sw,
                                                w1, w2, edge_ws, dist_ws, out);
}